// Round 6
// baseline (91.147 us; speedup 1.0000x reference)
//
#include <hip/hip_runtime.h>

#define KCENT 128
#define BLOCK 256
#define TN    64                   // Hermite table nodes (512 B LDS)
#define YMIN  (-9.0f)
#define YMAX  (9.0f)

#if __has_builtin(__builtin_amdgcn_exp2f)
#define EXP2F(x) __builtin_amdgcn_exp2f(x)
#else
#define EXP2F(x) exp2f(x)
#endif

// Single-kernel design. F(y) = sum_k w_k exp(-((y-c_k)g_k)^2) is 1-D in y, so
// each BLOCK builds a 64-node (F, F') table in-block (32 exps/thread: node =
// tid>>2, center-quarter = tid&3, shfl_xor reduce) — ~1.7e7 exps device-wide
// (~1.7us trans) vs 4e8 for direct eval. This removes R4's build kernel +
// inter-kernel launch gap (~5us of the 17.7us controllable budget).
// Per element: cubic Hermite interp of F (err ~4.4e-3 in F -> 4.6e-8 in out,
// threshold 2.1e-4), linear interp of F', RK4 with k2==k3 and 1st-order
// Taylor for stage-point RBF shifts (validated R1-R4, absmax 3.05e-5).

__device__ __forceinline__ float2 rk4_elem(float u, float yy,
                                           const float2* sF,
                                           float INVH, float H) {
    float tpos = (yy - YMIN) * INVH;
    int idx = (int)tpos;
    idx = idx < 0 ? 0 : (idx > TN - 2 ? TN - 2 : idx);
    float t = tpos - (float)idx;
    float2 n0 = sF[idx];
    float2 n1 = sF[idx + 1];
    float t2 = t * t, t3 = t2 * t;
    float h00 = 2.f * t3 - 3.f * t2 + 1.f;
    float h10 = t3 - 2.f * t2 + t;
    float h01 = 1.f - h00;
    float h11 = t3 - t2;
    float F = h00 * n0.x + h10 * (H * n0.y)
            + h01 * n1.x + h11 * (H * n1.y);
    float Fp = __builtin_fmaf(t, n1.y - n0.y, n0.y);

    const float INV95 = 1.0f / 95.45f;
    float s1 = (yy > 0.f) ? 1.f : ((yy < 0.f) ? -1.f : 0.f);
    float a1 = (u - yy * 214.9261f - 19.3607f * s1 - F + 3.2902f) * INV95;
    float dy = a1 * 0.001f;
    float h2 = 0.5f * dy;
    float y2 = yy + h2;             // k2 == k3 evaluation point
    float y4 = yy + dy;
    float rb2 = __builtin_fmaf(Fp, h2, F);   // 1st-order Taylor of F
    float rb4 = __builtin_fmaf(Fp, dy, F);
    float s2 = (y2 > 0.f) ? 1.f : ((y2 < 0.f) ? -1.f : 0.f);
    float a2 = (u - y2 * 214.9261f - 19.3607f * s2 - rb2 + 3.2902f) * INV95;
    float s4 = (y4 > 0.f) ? 1.f : ((y4 < 0.f) ? -1.f : 0.f);
    float a4 = (u - y4 * 214.9261f - 19.3607f * s4 - rb4 + 3.2902f) * INV95;

    const float DT6 = 0.001f / 6.0f;
    return make_float2(DT6 * (yy + 4.f * y2 + y4),
                       DT6 * (a1 + 4.f * a2 + a4));
}

__global__ __launch_bounds__(BLOCK, 8) void rk4_fused_kernel(
    const float* __restrict__ inputs,
    const float* __restrict__ states,
    const float* __restrict__ centers,
    const float* __restrict__ gammas,
    const float* __restrict__ weights,
    float* __restrict__ out, int B, int halfB)
{
    __shared__ float2 sF[TN];      // (F, F') per node — 512 B

    const int tid = threadIdx.x;
    const int p = blockIdx.x * BLOCK + tid;
    const bool valid = p < halfB;

    // Prefetch inputs FIRST: their HBM latency overlaps the table build.
    float2 uu = make_float2(0.f, 0.f);
    float4 ss = make_float4(0.f, 0.f, 0.f, 0.f);
    if (valid) {
        uu = ((const float2*)inputs)[p];
        ss = ((const float4*)states)[p];   // elems 2p, 2p+1
    }

    // ---- in-block table build: node = tid>>2 over center-quarter tid&3 ----
    const float SQRT_LOG2E = 1.2011224087864498f;  // sqrt(log2 e)
    const float TWO_LN2    = 1.3862943611198906f;  // 2 ln 2
    const float H    = (YMAX - YMIN) / (float)(TN - 1);
    const float INVH = 1.0f / H;
    {
        const int node = tid >> 2;
        const int q    = tid & 3;
        const float yn = YMIN + node * H;
        float F = 0.f, P = 0.f;
        #pragma unroll 8
        for (int j = 0; j < KCENT / 4; ++j) {
            const int k = q * (KCENT / 4) + j;
            float g  = gammas[k];
            float w  = weights[k];
            float a  = g * SQRT_LOG2E;
            float b  = a * centers[k];
            float x  = __builtin_fmaf(a, yn, -b);
            float ph = EXP2F(-(x * x));
            F = __builtin_fmaf(w, ph, F);
            P = __builtin_fmaf(-TWO_LN2 * a * w, x * ph, P);
        }
        // fold the 4 center-quarters (adjacent lanes)
        F += __shfl_xor(F, 1); P += __shfl_xor(P, 1);
        F += __shfl_xor(F, 2); P += __shfl_xor(P, 2);
        if (q == 0) sF[node] = make_float2(F, P);
    }
    __syncthreads();

    if (valid) {
        float2 ra = rk4_elem(uu.x, ss.y, sF, INVH, H);
        float2 rb = rk4_elem(uu.y, ss.w, sF, INVH, H);
        ((float4*)out)[p] = make_float4(ra.x, ra.y, rb.x, rb.y);
    }

    // odd-B tail (not hit for B = 1048576)
    if ((B & 1) && p == 0) {
        const int i = B - 1;
        float2 r = rk4_elem(inputs[i], ((const float2*)states)[i].y, sF, INVH, H);
        ((float2*)out)[i] = r;
    }
}

extern "C" void kernel_launch(void* const* d_in, const int* in_sizes, int n_in,
                              void* d_out, int out_size, void* d_ws, size_t ws_size,
                              hipStream_t stream) {
    const float* inputs  = (const float*)d_in[0];
    const float* states  = (const float*)d_in[1];
    const float* centers = (const float*)d_in[2];
    const float* gammas  = (const float*)d_in[3];
    const float* weights = (const float*)d_in[4];
    float* out = (float*)d_out;
    const int B = in_sizes[0];

    const int halfB = B >> 1;
    const int grid = (halfB + BLOCK - 1) / BLOCK;
    rk4_fused_kernel<<<grid > 0 ? grid : 1, BLOCK, 0, stream>>>(
        inputs, states, centers, gammas, weights, out, B, halfB);
}

// Round 7
// 74.901 us; speedup vs baseline: 1.2169x; 1.2169x over previous
//
#include <hip/hip_runtime.h>

#define KCENT 128
#define BLOCK 256
#define TN    64                   // Hermite table nodes (512 B LDS)
#define YMIN  (-9.0f)
#define YMAX  (9.0f)

#if __has_builtin(__builtin_amdgcn_exp2f)
#define EXP2F(x) __builtin_amdgcn_exp2f(x)
#else
#define EXP2F(x) exp2f(x)
#endif

// Single fused kernel. F(y) = sum_k w_k exp(-((y-c_k)g_k)^2) is 1-D in y:
// each block stages folded params (a,b,w,w2) to LDS (coalesced, once), builds
// a 64-node (F,F') Hermite table in-block (32 exps/thread via ds_read_b128
// broadcast), then evaluates 4 elements/thread by cubic-Hermite interp.
// R5 post-mortem: __launch_bounds__(256,8) forced a 64-VGPR cap -> scratch
// spill (+17us). No occupancy bound here; params via LDS not 96 VMEM
// loads/thread. Error: Hermite H^4/384*|F''''| ~ 4.4e-3 in F -> 4.6e-8 in
// output (threshold 2.1e-4); Taylor stage shift validated R1-R5 (3.05e-5).

__device__ __forceinline__ float2 rk4_elem(float u, float yy,
                                           const float2* sF,
                                           float INVH, float H) {
    float tpos = (yy - YMIN) * INVH;
    int idx = (int)tpos;
    idx = idx < 0 ? 0 : (idx > TN - 2 ? TN - 2 : idx);
    float t = tpos - (float)idx;
    float2 n0 = sF[idx];
    float2 n1 = sF[idx + 1];
    float t2 = t * t, t3 = t2 * t;
    float h00 = 2.f * t3 - 3.f * t2 + 1.f;
    float h10 = t3 - 2.f * t2 + t;
    float h01 = 1.f - h00;
    float h11 = t3 - t2;
    float F = h00 * n0.x + h10 * (H * n0.y)
            + h01 * n1.x + h11 * (H * n1.y);
    float Fp = __builtin_fmaf(t, n1.y - n0.y, n0.y);

    const float INV95 = 1.0f / 95.45f;
    float s1 = (yy > 0.f) ? 1.f : ((yy < 0.f) ? -1.f : 0.f);
    float a1 = (u - yy * 214.9261f - 19.3607f * s1 - F + 3.2902f) * INV95;
    float dy = a1 * 0.001f;
    float h2 = 0.5f * dy;
    float y2 = yy + h2;             // k2 == k3 evaluation point
    float y4 = yy + dy;
    float rb2 = __builtin_fmaf(Fp, h2, F);   // 1st-order Taylor of F
    float rb4 = __builtin_fmaf(Fp, dy, F);
    float s2 = (y2 > 0.f) ? 1.f : ((y2 < 0.f) ? -1.f : 0.f);
    float a2 = (u - y2 * 214.9261f - 19.3607f * s2 - rb2 + 3.2902f) * INV95;
    float s4 = (y4 > 0.f) ? 1.f : ((y4 < 0.f) ? -1.f : 0.f);
    float a4 = (u - y4 * 214.9261f - 19.3607f * s4 - rb4 + 3.2902f) * INV95;

    const float DT6 = 0.001f / 6.0f;
    return make_float2(DT6 * (yy + 4.f * y2 + y4),
                       DT6 * (a1 + 4.f * a2 + a4));
}

__global__ __launch_bounds__(BLOCK) void rk4_fused_kernel(
    const float* __restrict__ inputs,
    const float* __restrict__ states,
    const float* __restrict__ centers,
    const float* __restrict__ gammas,
    const float* __restrict__ weights,
    float* __restrict__ out, int B, int halfB)
{
    __shared__ float4 sPrm[KCENT]; // (a, b, w, w2) — 2 KB
    __shared__ float2 sF[TN];      // (F, F') per node — 512 B

    const int tid = threadIdx.x;
    const int p0 = blockIdx.x * (BLOCK * 2) + tid;
    const int p1 = p0 + BLOCK;
    const bool v0 = p0 < halfB, v1 = p1 < halfB;

    // Prefetch inputs FIRST: HBM latency overlaps param staging + build.
    float2 uu0 = make_float2(0.f, 0.f), uu1 = make_float2(0.f, 0.f);
    float4 ss0 = make_float4(0.f, 0.f, 0.f, 0.f);
    float4 ss1 = make_float4(0.f, 0.f, 0.f, 0.f);
    if (v0) { uu0 = ((const float2*)inputs)[p0];
              ss0 = ((const float4*)states)[p0]; }
    if (v1) { uu1 = ((const float2*)inputs)[p1];
              ss1 = ((const float4*)states)[p1]; }

    const float SQRT_LOG2E = 1.2011224087864498f;  // sqrt(log2 e)
    const float TWO_LN2    = 1.3862943611198906f;  // 2 ln 2
    const float H    = (YMAX - YMIN) / (float)(TN - 1);
    const float INVH = 1.0f / H;

    // ---- stage folded params to LDS (coalesced, once per block) ----
    if (tid < KCENT) {
        float g = gammas[tid];
        float w = weights[tid];
        float a = g * SQRT_LOG2E;
        sPrm[tid] = make_float4(a, a * centers[tid], w, -TWO_LN2 * a * w);
    }
    __syncthreads();

    // ---- in-block table build: node = tid>>2, center-quarter = tid&3 ----
    {
        const int node = tid >> 2;
        const int q    = tid & 3;
        const float yn = YMIN + node * H;
        float F = 0.f, P = 0.f;
        #pragma unroll 4
        for (int j = 0; j < KCENT / 4; ++j) {
            float4 c = sPrm[q * (KCENT / 4) + j];
            float x  = __builtin_fmaf(c.x, yn, -c.y);
            float ph = EXP2F(-(x * x));
            F = __builtin_fmaf(c.z, ph, F);
            P = __builtin_fmaf(c.w, x * ph, P);
        }
        F += __shfl_xor(F, 1); P += __shfl_xor(P, 1);
        F += __shfl_xor(F, 2); P += __shfl_xor(P, 2);
        if (q == 0) sF[node] = make_float2(F, P);
    }
    __syncthreads();

    if (v0) {
        float2 ra = rk4_elem(uu0.x, ss0.y, sF, INVH, H);
        float2 rb = rk4_elem(uu0.y, ss0.w, sF, INVH, H);
        ((float4*)out)[p0] = make_float4(ra.x, ra.y, rb.x, rb.y);
    }
    if (v1) {
        float2 ra = rk4_elem(uu1.x, ss1.y, sF, INVH, H);
        float2 rb = rk4_elem(uu1.y, ss1.w, sF, INVH, H);
        ((float4*)out)[p1] = make_float4(ra.x, ra.y, rb.x, rb.y);
    }

    // odd-B tail (not hit for B = 1048576)
    if ((B & 1) && p0 == 0) {
        const int i = B - 1;
        float2 r = rk4_elem(inputs[i], ((const float2*)states)[i].y, sF, INVH, H);
        ((float2*)out)[i] = r;
    }
}

extern "C" void kernel_launch(void* const* d_in, const int* in_sizes, int n_in,
                              void* d_out, int out_size, void* d_ws, size_t ws_size,
                              hipStream_t stream) {
    const float* inputs  = (const float*)d_in[0];
    const float* states  = (const float*)d_in[1];
    const float* centers = (const float*)d_in[2];
    const float* gammas  = (const float*)d_in[3];
    const float* weights = (const float*)d_in[4];
    float* out = (float*)d_out;
    const int B = in_sizes[0];

    const int halfB = B >> 1;
    const int per_block = BLOCK * 2;               // pairs per block
    const int grid = (halfB + per_block - 1) / per_block;
    rk4_fused_kernel<<<grid > 0 ? grid : 1, BLOCK, 0, stream>>>(
        inputs, states, centers, gammas, weights, out, B, halfB);
}